// Round 3
// baseline (4565.726 us; speedup 1.0000x reference)
//
#include <hip/hip_runtime.h>

// LSTMPricePredictor: B=4096, T=512, IN=1, H=50, 2 layers + FC(50->1)
// R3: weights in EXPLICIT named float4 registers (R1/R2 spilled arrays to
//     scratch: VGPR_Count=108). 512 blocks x 256 threads (TB=8 batch rows,
//     2 blocks/CU) so barrier drain of one block is hidden by the other.
// Wave w (0..3) owns gate rows g = 50*w + lane (lane<50) for ALL 8 batch rows.
// h-state in LDS, read with wave-uniform (broadcast) float4 loads.
// x tile (8x512 = 16 KB) staged in LDS once.

#define T_STEPS 512
#define HID 50
#define TB 8          // batch rows per block
#define PITCH0 52     // h0 row pitch (floats; 16B-aligned rows, pads zero)
#define PITCH1 104    // [h0_t ; h1_{t-1}] row pitch, cols 100..103 zero
#define GPITCH 200    // gates row pitch

__device__ __forceinline__ float sigm(float x) {
    return 1.0f / (1.0f + __expf(-x));
}
__device__ __forceinline__ float tanhh(float x) {
    return 1.0f - 2.0f / (1.0f + __expf(2.0f * x));
}

// ---- macro lists over the weight float4s ----
#define L13(F) F(0) F(1) F(2) F(3) F(4) F(5) F(6) F(7) F(8) F(9) F(10) F(11) F(12)
#define L26(F) F(0) F(1) F(2) F(3) F(4) F(5) F(6) F(7) F(8) F(9) F(10) F(11) F(12) \
               F(13) F(14) F(15) F(16) F(17) F(18) F(19) F(20) F(21) F(22) F(23) F(24) F(25)

extern "C" __global__ __launch_bounds__(256, 2)
void lstm2_fc_kernel(const float* __restrict__ x,
                     const float* __restrict__ W_ih0, const float* __restrict__ W_hh0,
                     const float* __restrict__ b_ih0, const float* __restrict__ b_hh0,
                     const float* __restrict__ W_ih1, const float* __restrict__ W_hh1,
                     const float* __restrict__ b_ih1, const float* __restrict__ b_hh1,
                     const float* __restrict__ fc_w, const float* __restrict__ fc_b,
                     float* __restrict__ out)
{
    __shared__ float xs[TB * T_STEPS];   // staged x tile: xs[b][t]
    __shared__ float h0s[TB * PITCH0];   // layer0 hidden h0_{t-1} (pads zero)
    __shared__ float hc1[TB * PITCH1];   // cols 0..49: h0_t, 50..99: h1_{t-1}
    __shared__ float gates[TB * GPITCH]; // gate pre-activations (both layers)

    const int tid  = threadIdx.x;
    const int lane = tid & 63;
    const int w    = tid >> 6;          // wave id 0..3 = gate quarter
    const int b0   = blockIdx.x * TB;

    // ---- stage x tile: rows b0..b0+7 are contiguous in x ----
    {
        const float4* xsrc4 = (const float4*)(x + b0 * T_STEPS);
        float4* xdst4 = (float4*)xs;
        #pragma unroll
        for (int k = 0; k < (TB * T_STEPS / 4) / 256; ++k)
            xdst4[tid + k * 256] = xsrc4[tid + k * 256];
    }

    // ---- zero-init LDS state (incl. pad columns; pads stay zero forever) ----
    for (int i = tid; i < TB * PITCH0; i += 256) h0s[i] = 0.0f;
    for (int i = tid; i < TB * PITCH1; i += 256) hc1[i] = 0.0f;

    // ---- weight rows into EXPLICIT float4 registers (loaded once) ----
    const bool is_gate = (lane < HID);
    const int  g = 50 * w + (is_gate ? lane : 49);   // clamped, always valid

    const float* r0h = W_hh0 + g * HID;   // 50 floats
    const float* r1i = W_ih1 + g * HID;   // 50 floats
    const float* r1h = W_hh1 + g * HID;   // 50 floats

    // element k of the 104-long layer-1 weight row [W_ih1_row | W_hh1_row | 0,0,0,0]
    auto ldW1 = [&](int k) -> float {
        if (k < HID)     return r1i[k];
        if (k < 2 * HID) return r1h[k - HID];
        return 0.0f;
    };
    auto ldW0 = [&](int k) -> float {
        return (k < HID) ? r0h[k] : 0.0f;
    };

    #define DECL0(i) float4 W0_##i;
    #define DECL1(i) float4 W1_##i;
    L13(DECL0)
    L26(DECL1)
    #define LOAD0(i) W0_##i = make_float4(ldW0(4*(i)), ldW0(4*(i)+1), ldW0(4*(i)+2), ldW0(4*(i)+3));
    #define LOAD1(i) W1_##i = make_float4(ldW1(4*(i)), ldW1(4*(i)+1), ldW1(4*(i)+2), ldW1(4*(i)+3));
    L13(LOAD0)
    L26(LOAD1)

    const float wih0 = W_ih0[g];
    const float bs0  = b_ih0[g] + b_hh0[g];
    const float bs1  = b_ih1[g] + b_hh1[g];

    // ---- elementwise-thread state: c for (b = 2w + {0,1}, k = lane) ----
    float c0r[2] = {0.0f, 0.0f};
    float c1r[2] = {0.0f, 0.0f};

    __syncthreads();

    #define FMA0(i) { float4 hv = h4[i]; ax += W0_##i.x*hv.x; ay += W0_##i.y*hv.y; \
                      az += W0_##i.z*hv.z; aw += W0_##i.w*hv.w; }
    #define FMA1(i) { float4 hv = h4[i]; ax += W1_##i.x*hv.x; ay += W1_##i.y*hv.y; \
                      az += W1_##i.z*hv.z; aw += W1_##i.w*hv.w; }

    for (int t = 0; t < T_STEPS; ++t) {
        // ---------- Phase A: layer-0 gates (all 8 rows per wave) ----------
        #pragma unroll 2
        for (int bb = 0; bb < TB; ++bb) {
            const float4* h4 = (const float4*)(h0s + bb * PITCH0);
            float ax = 0.f, ay = 0.f, az = 0.f, aw = 0.f;
            L13(FMA0)
            const float acc = bs0 + wih0 * xs[bb * T_STEPS + t] + ((ax + ay) + (az + aw));
            if (is_gate) gates[bb * GPITCH + g] = acc;
        }
        __syncthreads();

        // ---------- Phase B: layer-0 elementwise ----------
        if (is_gate) {
            #pragma unroll
            for (int bi = 0; bi < 2; ++bi) {
                const int b = 2 * w + bi;
                const float gi = gates[b * GPITCH + lane];
                const float gf = gates[b * GPITCH + 50 + lane];
                const float gc = gates[b * GPITCH + 100 + lane];
                const float go = gates[b * GPITCH + 150 + lane];
                const float i_ = sigm(gi);
                const float f_ = sigm(gf);
                const float c_ = tanhh(gc);
                const float o_ = sigm(go);
                const float cn = f_ * c0r[bi] + i_ * c_;
                c0r[bi] = cn;
                const float hn = o_ * tanhh(cn);
                h0s[b * PITCH0 + lane] = hn;   // next step's layer-0 recurrence
                hc1[b * PITCH1 + lane] = hn;   // layer-1 input (this step)
            }
        }
        __syncthreads();

        // ---------- Phase C: layer-1 gates (input = [h0_t ; h1_{t-1}]) ----------
        #pragma unroll 2
        for (int bb = 0; bb < TB; ++bb) {
            const float4* h4 = (const float4*)(hc1 + bb * PITCH1);
            float ax = 0.f, ay = 0.f, az = 0.f, aw = 0.f;
            L26(FMA1)
            const float acc = bs1 + ((ax + ay) + (az + aw));
            if (is_gate) gates[bb * GPITCH + g] = acc;
        }
        __syncthreads();

        // ---------- Phase D: layer-1 elementwise ----------
        if (is_gate) {
            #pragma unroll
            for (int bi = 0; bi < 2; ++bi) {
                const int b = 2 * w + bi;
                const float gi = gates[b * GPITCH + lane];
                const float gf = gates[b * GPITCH + 50 + lane];
                const float gc = gates[b * GPITCH + 100 + lane];
                const float go = gates[b * GPITCH + 150 + lane];
                const float i_ = sigm(gi);
                const float f_ = sigm(gf);
                const float c_ = tanhh(gc);
                const float o_ = sigm(go);
                const float cn = f_ * c1r[bi] + i_ * c_;
                c1r[bi] = cn;
                const float hn = o_ * tanhh(cn);
                hc1[b * PITCH1 + 50 + lane] = hn;   // h1_t -> next step
            }
        }
        __syncthreads();
    }

    // ---------- Final FC: out[b] = fc_b + fc_w . h1_{T-1}[b, :] ----------
    if (tid < TB) {
        const int b = tid;
        float s = fc_b[0];
        for (int k = 0; k < HID; ++k)
            s += fc_w[k] * hc1[b * PITCH1 + 50 + k];
        out[b0 + b] = s;
    }
}

extern "C" void kernel_launch(void* const* d_in, const int* in_sizes, int n_in,
                              void* d_out, int out_size, void* d_ws, size_t ws_size,
                              hipStream_t stream) {
    (void)in_sizes; (void)n_in; (void)d_ws; (void)ws_size; (void)out_size;
    const float* x     = (const float*)d_in[0];
    const float* W_ih0 = (const float*)d_in[1];
    const float* W_hh0 = (const float*)d_in[2];
    const float* b_ih0 = (const float*)d_in[3];
    const float* b_hh0 = (const float*)d_in[4];
    const float* W_ih1 = (const float*)d_in[5];
    const float* W_hh1 = (const float*)d_in[6];
    const float* b_ih1 = (const float*)d_in[7];
    const float* b_hh1 = (const float*)d_in[8];
    const float* fc_w  = (const float*)d_in[9];
    const float* fc_b  = (const float*)d_in[10];

    dim3 grid(4096 / TB);   // 512 blocks, 2 per CU
    dim3 block(256);        // 4 waves
    lstm2_fc_kernel<<<grid, block, 0, stream>>>(
        x, W_ih0, W_hh0, b_ih0, b_hh0,
        W_ih1, W_hh1, b_ih1, b_hh1,
        fc_w, fc_b, (float*)d_out);
}

// Round 4
// 4414.478 us; speedup vs baseline: 1.0343x; 1.0343x over previous
//
#include <hip/hip_runtime.h>

// LSTMPricePredictor: B=4096, T=512, IN=1, H=50, 2 layers + FC(50->1)
// R4: K-split gate waves. R1-R3 the compiler SANK the 156-float weight rows
//     back into the loop (loop-invariant global loads are legal to remat;
//     VGPR_Count stuck at 108-128). Fix: halve the per-thread weight
//     footprint to 80 floats so everything fits under 128 VGPRs and the
//     allocator has no pressure reason to sink.
// 512 blocks x 512 threads (8 waves), TB=8 batch rows/block, 2 blocks/CU.
// Wave w: gate-quarter q=w&3, k-half m=w>>2. Thread (w, lane<50) owns gate
//   g=50q+lane and accumulates the m-th half of the dot product; partial
//   sums land in LDS gp[m][row][200]; elementwise phase adds both halves.
// h-state in LDS (wave-uniform broadcast float4 reads); x tile staged once.

#define T_STEPS 512
#define HID 50
#define TB 8          // batch rows per block
#define P0 56         // h0 row pitch (14 float4; halves of 7 float4)
#define P1 104        // [h0_t ; h1_{t-1}] pitch (halves of 13 float4)
#define GP 200        // gates row pitch

__device__ __forceinline__ float sigm(float x) {
    return 1.0f / (1.0f + __expf(-x));
}
__device__ __forceinline__ float tanhh(float x) {
    return 1.0f - 2.0f / (1.0f + __expf(2.0f * x));
}

#define L7(F)  F(0) F(1) F(2) F(3) F(4) F(5) F(6)
#define L13(F) F(0) F(1) F(2) F(3) F(4) F(5) F(6) F(7) F(8) F(9) F(10) F(11) F(12)

extern "C" __global__ __launch_bounds__(512, 2)
void lstm2_fc_kernel(const float* __restrict__ x,
                     const float* __restrict__ W_ih0, const float* __restrict__ W_hh0,
                     const float* __restrict__ b_ih0, const float* __restrict__ b_hh0,
                     const float* __restrict__ W_ih1, const float* __restrict__ W_hh1,
                     const float* __restrict__ b_ih1, const float* __restrict__ b_hh1,
                     const float* __restrict__ fc_w, const float* __restrict__ fc_b,
                     float* __restrict__ out)
{
    __shared__ float xs[TB * T_STEPS];   // staged x tile: xs[b][t]  (16 KB)
    __shared__ float h0s[TB * P0];       // layer0 h_{t-1} (pads zero)
    __shared__ float hc1[TB * P1];       // [h0_t(50) | h1_{t-1}(50) | pad4]
    __shared__ float gp[2 * TB * GP];    // partial gates: [khalf][row][200]

    const int tid  = threadIdx.x;
    const int lane = tid & 63;
    const int w    = tid >> 6;          // wave 0..7
    const int q    = w & 3;             // gate quarter
    const int m    = w >> 2;            // k-half 0/1
    const int b0   = blockIdx.x * TB;

    // ---- stage x tile (rows b0..b0+7 contiguous in x since IN==1) ----
    {
        const float4* xsrc4 = (const float4*)(x + b0 * T_STEPS);
        float4* xdst4 = (float4*)xs;
        #pragma unroll
        for (int k = 0; k < (TB * T_STEPS / 4) / 512; ++k)
            xdst4[tid + k * 512] = xsrc4[tid + k * 512];
    }

    // ---- zero-init LDS h-state (incl. pads; pads never written again) ----
    for (int i = tid; i < TB * P0; i += 512) h0s[i] = 0.0f;
    for (int i = tid; i < TB * P1; i += 512) hc1[i] = 0.0f;

    // ---- weight half-rows into explicit float4 registers (once) ----
    const bool is_gate = (lane < HID);
    const int  g = 50 * q + (is_gate ? lane : 49);   // clamped, uniform control

    // element k of this thread's half-row
    auto ld0 = [&](int k) -> float {        // W_hh0 half (28 floats, pads 0)
        const int kk = m * 28 + k;
        return (kk < HID) ? W_hh0[g * HID + kk] : 0.0f;
    };
    auto ld1 = [&](int k) -> float {        // [W_ih1|W_hh1] half (52 floats)
        const int kk = m * 52 + k;
        if (kk < HID)     return W_ih1[g * HID + kk];
        if (kk < 2 * HID) return W_hh1[g * HID + kk - HID];
        return 0.0f;
    };

    #define DECL0(i) float4 W0_##i;
    #define DECL1(i) float4 W1_##i;
    L7(DECL0)
    L13(DECL1)
    #define LOAD0(i) W0_##i = make_float4(ld0(4*(i)), ld0(4*(i)+1), ld0(4*(i)+2), ld0(4*(i)+3));
    #define LOAD1(i) W1_##i = make_float4(ld1(4*(i)), ld1(4*(i)+1), ld1(4*(i)+2), ld1(4*(i)+3));
    L7(LOAD0)
    L13(LOAD1)

    const float wih0 = W_ih0[g];
    const float bs0  = b_ih0[g] + b_hh0[g];
    const float bs1  = b_ih1[g] + b_hh1[g];

    // elementwise state: thread (w, lane<50) owns c[row=w][k=lane], one per layer
    float c0 = 0.0f, c1 = 0.0f;

    __syncthreads();

    #define FMA0(i) { float4 hv = h4[i]; ax += W0_##i.x*hv.x; ay += W0_##i.y*hv.y; \
                      az += W0_##i.z*hv.z; aw += W0_##i.w*hv.w; }
    #define FMA1(i) { float4 hv = h4[i]; ax += W1_##i.x*hv.x; ay += W1_##i.y*hv.y; \
                      az += W1_##i.z*hv.z; aw += W1_##i.w*hv.w; }

    for (int t = 0; t < T_STEPS; ++t) {
        // ---------- Phase A: layer-0 partial gates ----------
        #pragma unroll
        for (int bb = 0; bb < TB; ++bb) {
            const float4* h4 = (const float4*)(h0s + bb * P0) + m * 7;
            float ax = 0.f, ay = 0.f, az = 0.f, aw = 0.f;
            L7(FMA0)
            float acc = (ax + ay) + (az + aw);
            if (m == 0) acc += bs0 + wih0 * xs[bb * T_STEPS + t];
            if (is_gate) gp[(m * TB + bb) * GP + g] = acc;
        }
        __syncthreads();

        // ---------- Phase B: layer-0 elementwise (row = wave id) ----------
        if (is_gate) {
            const int r = w;
            const float* g0 = gp + r * GP;
            const float* g1 = gp + (TB + r) * GP;
            const float gi = g0[lane]       + g1[lane];
            const float gf = g0[lane + 50]  + g1[lane + 50];
            const float gc = g0[lane + 100] + g1[lane + 100];
            const float go = g0[lane + 150] + g1[lane + 150];
            const float i_ = sigm(gi);
            const float f_ = sigm(gf);
            const float c_ = tanhh(gc);
            const float o_ = sigm(go);
            c0 = f_ * c0 + i_ * c_;
            const float hn = o_ * tanhh(c0);
            h0s[r * P0 + lane] = hn;   // next step's layer-0 recurrence
            hc1[r * P1 + lane] = hn;   // layer-1 input (this step)
        }
        __syncthreads();

        // ---------- Phase C: layer-1 partial gates ----------
        #pragma unroll
        for (int bb = 0; bb < TB; ++bb) {
            const float4* h4 = (const float4*)(hc1 + bb * P1 + m * 52);
            float ax = 0.f, ay = 0.f, az = 0.f, aw = 0.f;
            L13(FMA1)
            float acc = (ax + ay) + (az + aw);
            if (m == 0) acc += bs1;
            if (is_gate) gp[(m * TB + bb) * GP + g] = acc;
        }
        __syncthreads();

        // ---------- Phase D: layer-1 elementwise ----------
        if (is_gate) {
            const int r = w;
            const float* g0 = gp + r * GP;
            const float* g1 = gp + (TB + r) * GP;
            const float gi = g0[lane]       + g1[lane];
            const float gf = g0[lane + 50]  + g1[lane + 50];
            const float gc = g0[lane + 100] + g1[lane + 100];
            const float go = g0[lane + 150] + g1[lane + 150];
            const float i_ = sigm(gi);
            const float f_ = sigm(gf);
            const float c_ = tanhh(gc);
            const float o_ = sigm(go);
            c1 = f_ * c1 + i_ * c_;
            const float hn = o_ * tanhh(c1);
            hc1[r * P1 + 50 + lane] = hn;   // h1_t -> next step
        }
        __syncthreads();
    }

    // ---------- Final FC: out[b] = fc_b + fc_w . h1_{T-1}[b,:] ----------
    if (tid < TB) {
        const int b = tid;
        float s = fc_b[0];
        for (int k = 0; k < HID; ++k)
            s += fc_w[k] * hc1[b * P1 + 50 + k];
        out[b0 + b] = s;
    }
}

extern "C" void kernel_launch(void* const* d_in, const int* in_sizes, int n_in,
                              void* d_out, int out_size, void* d_ws, size_t ws_size,
                              hipStream_t stream) {
    (void)in_sizes; (void)n_in; (void)d_ws; (void)ws_size; (void)out_size;
    const float* x     = (const float*)d_in[0];
    const float* W_ih0 = (const float*)d_in[1];
    const float* W_hh0 = (const float*)d_in[2];
    const float* b_ih0 = (const float*)d_in[3];
    const float* b_hh0 = (const float*)d_in[4];
    const float* W_ih1 = (const float*)d_in[5];
    const float* W_hh1 = (const float*)d_in[6];
    const float* b_ih1 = (const float*)d_in[7];
    const float* b_hh1 = (const float*)d_in[8];
    const float* fc_w  = (const float*)d_in[9];
    const float* fc_b  = (const float*)d_in[10];

    dim3 grid(4096 / TB);   // 512 blocks, 2 per CU
    dim3 block(512);        // 8 waves
    lstm2_fc_kernel<<<grid, block, 0, stream>>>(
        x, W_ih0, W_hh0, b_ih0, b_hh0,
        W_ih1, W_hh1, b_ih1, b_hh1,
        fc_w, fc_b, (float*)d_out);
}